// Round 11
// baseline (332.080 us; speedup 1.0000x reference)
//
#include <hip/hip_runtime.h>
#include <hip/hip_bf16.h>
#include <math.h>

#define HW 102400        // 320*320
#define KSEL 4096
#define CAP 16384

// ---------- helpers ----------
__device__ inline unsigned fkey(float f) {
    unsigned u = __float_as_uint(f);
    return (u & 0x80000000u) ? ~u : (u | 0x80000000u);
}

// wave64 sum via DPP (row_shr 1/2/4/8 + row_bcast 15/31); result valid in lane 63,
// returned through readlane -> SGPR (wave-uniform, enables scalar branch).
__device__ inline unsigned wave_sum64_s(unsigned x) {
    x += (unsigned)__builtin_amdgcn_update_dpp(0, (int)x, 0x111, 0xf, 0xf, false);
    x += (unsigned)__builtin_amdgcn_update_dpp(0, (int)x, 0x112, 0xf, 0xf, false);
    x += (unsigned)__builtin_amdgcn_update_dpp(0, (int)x, 0x114, 0xf, 0xf, false);
    x += (unsigned)__builtin_amdgcn_update_dpp(0, (int)x, 0x118, 0xf, 0xf, false);
    x += (unsigned)__builtin_amdgcn_update_dpp(0, (int)x, 0x142, 0xa, 0xf, false);
    x += (unsigned)__builtin_amdgcn_update_dpp(0, (int)x, 0x143, 0xc, 0xf, false);
    return (unsigned)__builtin_amdgcn_readlane((int)x, 63);
}

__device__ inline unsigned long long readlane64(unsigned long long v, int l) {
    unsigned lo = (unsigned)__builtin_amdgcn_readlane((int)(unsigned)(v & 0xffffffffull), l);
    unsigned hi = (unsigned)__builtin_amdgcn_readlane((int)(unsigned)(v >> 32), l);
    return ((unsigned long long)hi << 32) | lo;
}

// ---------- K1: score + class argmax + fused histogram (finite-only) ----------
// Finite-only atomic: the -inf same-address bin was the round-5 poison; finite
// keys spread over thousands of bins. Accumulation = exact sequential c=0..255
// fmaf chain (bit-stable across rounds, absmax 0.0).
__global__ __launch_bounds__(256) void k_score(const float* __restrict__ x,
                                               const float* __restrict__ sm,
                                               float* __restrict__ score,
                                               int* __restrict__ clsidx,
                                               unsigned* __restrict__ hist) {
    __shared__ float swt[256][16];      // 16KB: swt[c][k] = sm[k*256+c]
    __shared__ float tile[2][16][256];  // 32KB
    int t = threadIdx.x;
    for (int i = t; i < 4096; i += 256) {
        int k = i >> 8, c = i & 255;
        swt[c][k] = sm[i];
    }
    int wave = t >> 6, lane = t & 63;
    size_t pxb = (size_t)blockIdx.x * 256;
    const float* xc = x + (size_t)5 * HW + pxb;

    float acc[16];
#pragma unroll
    for (int k = 0; k < 16; ++k) acc[k] = 0.f;

    float4 sa[4], sb[4];

#define LOADX(dst, ti)                                                         \
    _Pragma("unroll") for (int j = 0; j < 4; ++j)                              \
        dst[j] = *(const float4*)(xc + (size_t)((ti) * 16 + wave * 4 + j) * HW + lane * 4);
#define STOREX(src, s)                                                         \
    _Pragma("unroll") for (int j = 0; j < 4; ++j)                              \
        ((float4*)&tile[s][wave * 4 + j][0])[lane] = src[j];
#define COMP(s, ti)                                                            \
    _Pragma("unroll") for (int cc = 0; cc < 16; ++cc) {                        \
        float xv = tile[s][cc][t];                                             \
        const float4* w4 = (const float4*)&swt[(ti) * 16 + cc][0];             \
        float4 w0 = w4[0], w1 = w4[1], w2 = w4[2], w3 = w4[3];                 \
        acc[0]  = fmaf(xv, w0.x, acc[0]);  acc[1]  = fmaf(xv, w0.y, acc[1]);   \
        acc[2]  = fmaf(xv, w0.z, acc[2]);  acc[3]  = fmaf(xv, w0.w, acc[3]);   \
        acc[4]  = fmaf(xv, w1.x, acc[4]);  acc[5]  = fmaf(xv, w1.y, acc[5]);   \
        acc[6]  = fmaf(xv, w1.z, acc[6]);  acc[7]  = fmaf(xv, w1.w, acc[7]);   \
        acc[8]  = fmaf(xv, w2.x, acc[8]);  acc[9]  = fmaf(xv, w2.y, acc[9]);   \
        acc[10] = fmaf(xv, w2.z, acc[10]); acc[11] = fmaf(xv, w2.w, acc[11]);  \
        acc[12] = fmaf(xv, w3.x, acc[12]); acc[13] = fmaf(xv, w3.y, acc[13]);  \
        acc[14] = fmaf(xv, w3.z, acc[14]); acc[15] = fmaf(xv, w3.w, acc[15]);  \
    }

    LOADX(sa, 0);
    STOREX(sa, 0);
    LOADX(sa, 1);
    LOADX(sb, 2);
    __syncthreads();

#pragma unroll
    for (int k = 0; k < 16; k += 2) {
        COMP(k & 1, k);
        STOREX(sa, (k + 1) & 1);
        if (k + 3 < 16) LOADX(sa, k + 3);
        __syncthreads();
        COMP((k + 1) & 1, k + 1);
        if (k + 2 < 16) { STOREX(sb, k & 1); }
        if (k + 4 < 16) LOADX(sb, k + 4);
        __syncthreads();
    }
#undef LOADX
#undef STOREX
#undef COMP

    float mv = acc[0]; int mi = 0;
#pragma unroll
    for (int k = 1; k < 16; ++k)
        if (acc[k] > mv) { mv = acc[k]; mi = k; }
    int n = (int)pxb + t;
    float x0 = x[n];
    float sig = 1.0f / (1.0f + expf(-x0));
    float sc = (sig > 0.5f) ? sig * mv : -INFINITY;
    score[n] = sc;
    clsidx[n] = mi;
    if (sc != -INFINITY) atomicAdd(&hist[fkey(sc) >> 16], 1u);
}

// ---------- K3: find 16-bit prefix p16 such that count(key>>16 >= p16) >= K ----------
__global__ __launch_bounds__(1024) void k_findp(const unsigned* __restrict__ hist,
                                                unsigned* __restrict__ meta) {
    __shared__ unsigned part[1024];
    __shared__ unsigned sgrp, s_after;
    __shared__ unsigned bins[64];
    int t = threadIdx.x;
    if (t == 0) { sgrp = 0; s_after = 0; }
    unsigned s = 0;
    const unsigned* hp = hist + t * 64;
    for (int i = 0; i < 64; ++i) s += hp[i];
    part[t] = s;
    __syncthreads();
    for (int off = 1; off < 1024; off <<= 1) {
        unsigned v = (t + off < 1024) ? part[t + off] : 0u;
        __syncthreads();
        part[t] += v;
        __syncthreads();
    }
    if (part[t] >= KSEL && (t == 1023 || part[t + 1] < KSEL)) {
        sgrp = (unsigned)t;
        s_after = (t == 1023) ? 0u : part[t + 1];
    }
    __syncthreads();
    unsigned g = sgrp, SA = s_after;
    if (t < 64) bins[t] = hist[g * 64 + t];
    __syncthreads();
    if (t == 0) {
        unsigned acc = SA, p = g * 64;
        for (int b = 63; b >= 0; --b) {
            acc += bins[b];
            if (acc >= KSEL) { p = g * 64 + (unsigned)b; break; }
        }
        meta[1] = p;
    }
}

// ---------- K4: collect candidates with key>>16 >= p16 ----------
__global__ void k_collect(const float* __restrict__ score,
                          unsigned* __restrict__ meta,
                          unsigned long long* __restrict__ cand) {
    int n = blockIdx.x * 256 + threadIdx.x;
    unsigned key = fkey(score[n]);
    if ((key >> 16) >= meta[1]) {
        unsigned pos = atomicAdd(&meta[0], 1u);
        if (pos < CAP)
            cand[pos] = ((unsigned long long)key << 32) | (unsigned)(~(unsigned)n);
    }
}

// ---------- K5: rank candidates (exact top-k ordering) + gather ----------
__global__ __launch_bounds__(256) void k_rank(const unsigned long long* __restrict__ cand,
                                              const unsigned* __restrict__ meta,
                                              const float* __restrict__ x,
                                              const float* __restrict__ score,
                                              const int* __restrict__ clsidx,
                                              float* __restrict__ topv,
                                              float* __restrict__ bl, float* __restrict__ bt,
                                              float* __restrict__ br, float* __restrict__ bb,
                                              float* __restrict__ area, int* __restrict__ clsk) {
    __shared__ unsigned long long tile[1024];
    int C = (int)meta[0]; if (C > CAP) C = CAP;
    int j = blockIdx.x * 256 + threadIdx.x;
    unsigned long long kj = (j < C) ? cand[j] : 0ull;
    unsigned rank = 0;
    for (int tb = 0; tb < C; tb += 1024) {
        int cnt = min(1024, C - tb);
        __syncthreads();
        for (int u = threadIdx.x; u < cnt; u += 256) tile[u] = cand[tb + u];
        __syncthreads();
        if (j < C)
            for (int u = 0; u < cnt; ++u) rank += (tile[u] > kj) ? 1u : 0u;
    }
    if (j < C && rank < KSEL) {
        unsigned n = ~(unsigned)(kj & 0xFFFFFFFFull);
        float l  = x[(size_t)1 * HW + n];
        float tt = x[(size_t)2 * HW + n];
        float r  = x[(size_t)3 * HW + n];
        float b  = x[(size_t)4 * HW + n];
        topv[rank] = score[n];
        bl[rank] = l; bt[rank] = tt; br[rank] = r; bb[rank] = b;
        area[rank] = (r - l) * (b - tt);
        clsk[rank] = clsidx[n];
    }
}

// ---------- K6: pairwise IoU >= 0.2 bitmask, ROW-MAJOR mask[i][w] ----------
__global__ __launch_bounds__(256) void k_mask(const float* __restrict__ bl, const float* __restrict__ bt,
                                              const float* __restrict__ br, const float* __restrict__ bb,
                                              const float* __restrict__ area,
                                              unsigned long long* __restrict__ mask) {
    __shared__ float sl[256], st[256], sr[256], sb[256], sa[256];
    int t = threadIdx.x;
    int ic = blockIdx.x >> 4;
    int jc = blockIdx.x & 15;
    int i = ic * 256 + t;
    int j0 = jc * 256;
    sl[t] = bl[j0 + t]; st[t] = bt[j0 + t]; sr[t] = br[j0 + t];
    sb[t] = bb[j0 + t]; sa[t] = area[j0 + t];
    __syncthreads();
    float li = bl[i], ti = bt[i], ri = br[i], bi = bb[i], ai = area[i];
#pragma unroll
    for (int w = 0; w < 4; ++w) {
        unsigned long long m = 0;
        for (int k2 = 0; k2 < 64; ++k2) {
            int j = w * 64 + k2;
            float iw = fminf(ri, sr[j]) - fmaxf(li, sl[j]); iw = fmaxf(iw, 0.f);
            float ih = fminf(bi, sb[j]) - fmaxf(ti, st[j]); ih = fmaxf(ih, 0.f);
            float inter = iw * ih;
            float uni = ai + sa[j] - inter + 1e-10f;
            if (inter / uni >= 0.2f) m |= (1ull << k2);
        }
        mask[(size_t)i * 64 + (jc * 4 + w)] = m;
    }
}

// ---------- K7: overlapped speculative NMS (verify(b) || prescan(b+1)) + epilogue ----------
// Pre-scan count is an UPPER BOUND of the exact count at verify time (alive only
// shrinks; &-masking bitwise-monotone), so prescan may read a stale / racily
// updated aliveL. Accepted set = exact ordered verify by wave 0 -> deterministic.
// 3 LDS row buffers; counted vmcnt(8) (vmcnt(0) tail); 2 barriers/iter.
// Swizzle: logical word w of row r at phys (w + 2r) & 63 (stage source permuted).
__global__ __launch_bounds__(256, 1) void k_nms(const unsigned long long* __restrict__ mask,
                                                const float* __restrict__ topv,
                                                const float* __restrict__ area,
                                                const float* __restrict__ bl, const float* __restrict__ bt,
                                                const float* __restrict__ br, const float* __restrict__ bb,
                                                const int* __restrict__ clsk,
                                                const float* __restrict__ padding,
                                                const float* __restrict__ ratio,
                                                const int* __restrict__ piw, const int* __restrict__ pih,
                                                float* __restrict__ out) {
    __shared__ unsigned long long rowsL[3][4096];   // 96 KB
    __shared__ unsigned long long aliveL[64];
    __shared__ unsigned long long keptL[64];
    __shared__ unsigned cntP[2][64][3];             // [phase][row][part]
    int t = threadIdx.x;
    int lane = t & 63;
    int W = t >> 6;

#define STAGE(bb, s)                                                            \
    do {                                                                        \
        _Pragma("unroll") for (int i_ = 0; i_ < 8; ++i_) {                      \
            int seg_ = i_ * 4 + W;                                              \
            int r_ = seg_ * 2 + (lane >> 5);                                    \
            int p_ = (lane & 31) * 2;                                           \
            int wl_ = (p_ - 2 * r_) & 63;                                       \
            const unsigned long long* gp_ =                                     \
                mask + ((size_t)((bb) * 64 + r_) * 64 + wl_);                   \
            __builtin_amdgcn_global_load_lds(                                   \
                (const __attribute__((address_space(1))) void*)gp_,             \
                (__attribute__((address_space(3))) void*)&rowsL[s][seg_ * 128], \
                16, 0, 0);                                                      \
        }                                                                       \
    } while (0)

    // prescan batch BB (waves 1-3): thread (row j, part p) counts its word range
    // against (racy-stale) aliveL -> cntP[BB&1][j][p]. Upper bound by monotonicity.
#define PRESCAN(BB)                                                             \
    do {                                                                        \
        int u_ = t - 64;                                                        \
        int j_ = u_ & 63;                                                       \
        int p_ = u_ >> 6;                                                       \
        const unsigned long long* rb_ = &rowsL[(BB) % 3][0];                    \
        int q0_ = (p_ == 0) ? 0 : (p_ == 1) ? 11 : 22;                          \
        int qN_ = (p_ == 2) ? 10 : 11;                                          \
        unsigned long long pfx_ = (j_ == 63) ? ~0ull : ((1ull << (j_ + 1)) - 1ull); \
        unsigned cnt_ = 0;                                                      \
        for (int q_ = q0_; q_ < q0_ + qN_; ++q_) {                              \
            int wl_ = q_ * 2;                                                   \
            int ph_ = (wl_ + 2 * j_) & 63;                                      \
            ulonglong2 rv_ = *(const ulonglong2*)&rb_[j_ * 64 + ph_];           \
            ulonglong2 av_ = *(const ulonglong2*)&aliveL[wl_];                  \
            unsigned long long ax_ = rv_.x & av_.x, ay_ = rv_.y & av_.y;        \
            cnt_ += (unsigned)__popcll(ax_) + (unsigned)__popcll(ay_);          \
            if (wl_ == (BB))     cnt_ -= (unsigned)__popcll(ax_ & pfx_);        \
            if (wl_ + 1 == (BB)) cnt_ -= (unsigned)__popcll(ay_ & pfx_);        \
        }                                                                       \
        cntP[(BB) & 1][j_][p_] = cnt_;                                          \
    } while (0)

#define VER(jj, rw)                                                            \
    {                                                                          \
        unsigned long long awc = readlane64(alive, b);                         \
        if ((awc >> (jj)) & 1ull) {                                            \
            unsigned long long awAdj = alive;                                  \
            unsigned long long pm = ((jj) == 63) ? ~0ull                       \
                                                 : ((1ull << ((jj) + 1)) - 1ull); \
            if (lane == b) awAdj &= ~pm;                                       \
            unsigned c_ = (unsigned)__popcll((rw) & awAdj);                    \
            unsigned tt_ = wave_sum64_s(c_);                                   \
            if (tt_ >= 10u) { alive &= ~(rw); keptB |= 1ull << (jj); }         \
        }                                                                      \
    }

    // ---- init: wave0 builds register-distributed alive/areaok
    unsigned long long alive = 0, areaok = 0;
    if (W == 0) {
        for (int k = 0; k < 64; ++k) {
            float tv = topv[(size_t)k * 64 + lane];
            float ar = area[(size_t)k * 64 + lane];
            unsigned long long b1 = __ballot(tv != -INFINITY);
            unsigned long long b2 = __ballot(ar >= 4.0f);
            if (lane == k) { alive = b1; areaok = b2; }
        }
    }
    STAGE(0, 0);
    STAGE(1, 1);
    if (W == 0) aliveL[lane] = alive;
    asm volatile("s_waitcnt lgkmcnt(0)" ::: "memory");
    asm volatile("s_waitcnt vmcnt(8)" ::: "memory");   // buf0 landed (per wave)
    __builtin_amdgcn_sched_barrier(0);
    __builtin_amdgcn_s_barrier();                      // aliveL + buf0 (all waves)

    STAGE(2, 2);
    if (W > 0) PRESCAN(0);
    asm volatile("s_waitcnt lgkmcnt(0)" ::: "memory");
    __builtin_amdgcn_s_barrier();                      // cntP[0] visible

    for (int b = 0; b < 64; ++b) {
        if (b <= 61) asm volatile("s_waitcnt vmcnt(8)" ::: "memory");
        else         asm volatile("s_waitcnt vmcnt(0)" ::: "memory");
        __builtin_amdgcn_sched_barrier(0);
        __builtin_amdgcn_s_barrier();                  // buf(b+1) landed (all waves)

        if (W == 0) {
            // ---- exact ordered verify of batch b
            const unsigned long long* rb = &rowsL[b % 3][0];
            unsigned myc = cntP[b & 1][lane][0] + cntP[b & 1][lane][1] + cntP[b & 1][lane][2];
            unsigned long long aw0snap = readlane64(alive, b);
            unsigned long long areaok0 = readlane64(areaok, b);
            bool candp = (myc >= 10u) && ((areaok0 >> lane) & 1ull) &&
                         ((aw0snap >> lane) & 1ull);
            unsigned long long cand = __ballot(candp);
            unsigned long long keptB = 0;
            while (cand) {
                int j1 = __ffsll(cand) - 1; cand &= cand - 1;
                int j2 = -1, j3 = -1, j4 = -1;
                if (cand) { j2 = __ffsll(cand) - 1; cand &= cand - 1; }
                if (cand) { j3 = __ffsll(cand) - 1; cand &= cand - 1; }
                if (cand) { j4 = __ffsll(cand) - 1; cand &= cand - 1; }
                unsigned long long r1 = rb[j1 * 64 + ((lane + 2 * j1) & 63)];
                unsigned long long r2 = (j2 >= 0) ? rb[j2 * 64 + ((lane + 2 * j2) & 63)] : 0;
                unsigned long long r3 = (j3 >= 0) ? rb[j3 * 64 + ((lane + 2 * j3) & 63)] : 0;
                unsigned long long r4 = (j4 >= 0) ? rb[j4 * 64 + ((lane + 2 * j4) & 63)] : 0;
                VER(j1, r1);
                if (j2 >= 0) VER(j2, r2);
                if (j3 >= 0) VER(j3, r3);
                if (j4 >= 0) VER(j4, r4);
            }
            if (lane == b) alive = 0;                  // word b fully visited
            if (lane == 0) keptL[b] = keptB;
            aliveL[lane] = alive;                      // racy mirror (legal: upper bound)
        } else if (b < 63) {
            PRESCAN(b + 1);
        }
        asm volatile("s_waitcnt lgkmcnt(0)" ::: "memory");
        __builtin_amdgcn_s_barrier();                  // cntP/keptL/aliveL visible; buf(b%3) free
        if (b + 3 < 64) STAGE(b + 3, (b + 3) % 3);
    }

    // ---- fused epilogue (was k_out)
    float p0 = padding[0], p1 = padding[1];
    float invr = 1.0f / ratio[0];
    float Wimg = (float)piw[0], Himg = (float)pih[0];
    for (int i = t; i < KSEL; i += 256) {
        bool kept = (keptL[i >> 6] >> (i & 63)) & 1ull;
        float tv = topv[i];
        bool keep = kept && (tv >= 0.5f);
        float x1 = fmaxf((bl[i] - p0) * invr, 0.f);
        float y1 = fmaxf((bt[i] - p1) * invr, 0.f);
        float x2 = fminf((br[i] - p0) * invr, Wimg);
        float y2 = fminf((bb[i] - p1) * invr, Himg);
        keep = keep && (x1 < Wimg) && (y1 < Himg);
        float* o = out + (size_t)i * 7;
        if (keep) {
            o[0] = 1.0f; o[1] = tv; o[2] = x1; o[3] = y1; o[4] = x2; o[5] = y2;
            o[6] = (float)clsk[i];
        } else {
            o[0] = 0.f; o[1] = 0.f; o[2] = 0.f; o[3] = 0.f; o[4] = 0.f; o[5] = 0.f; o[6] = 0.f;
        }
    }
#undef STAGE
#undef PRESCAN
#undef VER
}

extern "C" void kernel_launch(void* const* d_in, const int* in_sizes, int n_in,
                              void* d_out, int out_size, void* d_ws, size_t ws_size,
                              hipStream_t stream) {
    const float* x       = (const float*)d_in[0];
    const float* sm      = (const float*)d_in[1];
    const float* padding = (const float*)d_in[2];
    const float* ratio   = (const float*)d_in[3];
    const int*   piw     = (const int*)d_in[4];
    const int*   pih     = (const int*)d_in[5];
    float* out = (float*)d_out;
    char* ws = (char*)d_ws;

    // workspace layout (bytes)
    float* score               = (float*)(ws + 0);                 // 409600
    int*   clsidx              = (int*)(ws + 409600);              // 409600
    unsigned* hist             = (unsigned*)(ws + 819200);         // 262144
    unsigned* meta             = (unsigned*)(ws + 1081344);        // 512 (meta[0]=counter, meta[1]=p16)
    unsigned long long* cand   = (unsigned long long*)(ws + 1081856); // CAP*8 = 131072
    float* topv                = (float*)(ws + 1212928);           // 16384
    float* bl                  = (float*)(ws + 1229312);
    float* bt                  = (float*)(ws + 1245696);
    float* br                  = (float*)(ws + 1262080);
    float* bb                  = (float*)(ws + 1278464);
    float* area                = (float*)(ws + 1294848);
    int*   clsk                = (int*)(ws + 1311232);
    unsigned long long* mask   = (unsigned long long*)(ws + 1328128); // 2097152

    hipMemsetAsync(hist, 0, 262144 + 512, stream);  // hist + meta

    k_score  <<<400, 256, 0, stream>>>(x, sm, score, clsidx, hist);
    k_findp  <<<1, 1024, 0, stream>>>(hist, meta);
    k_collect<<<400, 256, 0, stream>>>(score, meta, cand);
    k_rank   <<<CAP / 256, 256, 0, stream>>>(cand, meta, x, score, clsidx,
                                             topv, bl, bt, br, bb, area, clsk);
    k_mask   <<<256, 256, 0, stream>>>(bl, bt, br, bb, area, mask);
    k_nms    <<<1, 256, 0, stream>>>(mask, topv, area, bl, bt, br, bb, clsk,
                                     padding, ratio, piw, pih, out);
}

// Round 12
// 312.229 us; speedup vs baseline: 1.0636x; 1.0636x over previous
//
#include <hip/hip_runtime.h>
#include <hip/hip_bf16.h>
#include <math.h>

#define HW 102400        // 320*320
#define KSEL 4096
#define CAP 16384

// ---------- helpers ----------
__device__ inline unsigned fkey(float f) {
    unsigned u = __float_as_uint(f);
    return (u & 0x80000000u) ? ~u : (u | 0x80000000u);
}

// wave64 sum via DPP (row_shr 1/2/4/8 + row_bcast 15/31); result valid in lane 63,
// returned through readlane -> SGPR (wave-uniform, enables scalar branch).
__device__ inline unsigned wave_sum64_s(unsigned x) {
    x += (unsigned)__builtin_amdgcn_update_dpp(0, (int)x, 0x111, 0xf, 0xf, false);
    x += (unsigned)__builtin_amdgcn_update_dpp(0, (int)x, 0x112, 0xf, 0xf, false);
    x += (unsigned)__builtin_amdgcn_update_dpp(0, (int)x, 0x114, 0xf, 0xf, false);
    x += (unsigned)__builtin_amdgcn_update_dpp(0, (int)x, 0x118, 0xf, 0xf, false);
    x += (unsigned)__builtin_amdgcn_update_dpp(0, (int)x, 0x142, 0xa, 0xf, false);
    x += (unsigned)__builtin_amdgcn_update_dpp(0, (int)x, 0x143, 0xc, 0xf, false);
    return (unsigned)__builtin_amdgcn_readlane((int)x, 63);
}

__device__ inline unsigned long long readlane64(unsigned long long v, int l) {
    unsigned lo = (unsigned)__builtin_amdgcn_readlane((int)(unsigned)(v & 0xffffffffull), l);
    unsigned hi = (unsigned)__builtin_amdgcn_readlane((int)(unsigned)(v >> 32), l);
    return ((unsigned long long)hi << 32) | lo;
}

// ---------- K1: score + class argmax + fused histogram (finite-only) ----------
// 800 blocks x 128 threads (2x TLP vs r11). Block = 128 pixels; 16-channel LDS
// tiles (2 bufs, 8 KB each), 1 barrier per tile, 2-deep register prefetch.
// Accumulation = exact sequential c=0..255 fmaf chain (bit-stable, absmax 0.0).
__global__ __launch_bounds__(128) void k_score(const float* __restrict__ x,
                                               const float* __restrict__ sm,
                                               float* __restrict__ score,
                                               int* __restrict__ clsidx,
                                               unsigned* __restrict__ hist) {
    __shared__ float swt[256][16];      // 16KB: swt[c][k] = sm[k*256+c]
    __shared__ float tile[2][16][128];  // 16KB
    int t = threadIdx.x;
    for (int i = t; i < 4096; i += 128) {
        int k = i >> 8, c = i & 255;
        swt[c][k] = sm[i];
    }
    int cg = t >> 5;          // channel subgroup 0..3
    int le = t & 31;          // float4 slot within 512B channel row
    size_t pxb = (size_t)blockIdx.x * 128;
    const float* xc = x + (size_t)5 * HW + pxb;

    float acc[16];
#pragma unroll
    for (int k = 0; k < 16; ++k) acc[k] = 0.f;

    float4 sa[4], sb[4];

#define LOADX(dst, ti)                                                         \
    _Pragma("unroll") for (int j = 0; j < 4; ++j)                              \
        dst[j] = *(const float4*)(xc + (size_t)((ti) * 16 + 4 * j + cg) * HW + le * 4);
#define STOREX(src, s)                                                         \
    _Pragma("unroll") for (int j = 0; j < 4; ++j)                              \
        ((float4*)&tile[s][4 * j + cg][0])[le] = src[j];
#define COMP(s, ti)                                                            \
    _Pragma("unroll") for (int cc = 0; cc < 16; ++cc) {                        \
        float xv = tile[s][cc][t];                                             \
        const float4* w4 = (const float4*)&swt[(ti) * 16 + cc][0];             \
        float4 w0 = w4[0], w1 = w4[1], w2 = w4[2], w3 = w4[3];                 \
        acc[0]  = fmaf(xv, w0.x, acc[0]);  acc[1]  = fmaf(xv, w0.y, acc[1]);   \
        acc[2]  = fmaf(xv, w0.z, acc[2]);  acc[3]  = fmaf(xv, w0.w, acc[3]);   \
        acc[4]  = fmaf(xv, w1.x, acc[4]);  acc[5]  = fmaf(xv, w1.y, acc[5]);   \
        acc[6]  = fmaf(xv, w1.z, acc[6]);  acc[7]  = fmaf(xv, w1.w, acc[7]);   \
        acc[8]  = fmaf(xv, w2.x, acc[8]);  acc[9]  = fmaf(xv, w2.y, acc[9]);   \
        acc[10] = fmaf(xv, w2.z, acc[10]); acc[11] = fmaf(xv, w2.w, acc[11]);  \
        acc[12] = fmaf(xv, w3.x, acc[12]); acc[13] = fmaf(xv, w3.y, acc[13]);  \
        acc[14] = fmaf(xv, w3.z, acc[14]); acc[15] = fmaf(xv, w3.w, acc[15]);  \
    }

    LOADX(sa, 0);
    STOREX(sa, 0);
    LOADX(sa, 1);
    LOADX(sb, 2);
    __syncthreads();

#pragma unroll
    for (int k = 0; k < 16; k += 2) {
        COMP(k & 1, k);
        STOREX(sa, (k + 1) & 1);
        if (k + 3 < 16) LOADX(sa, k + 3);
        __syncthreads();
        COMP((k + 1) & 1, k + 1);
        if (k + 2 < 16) { STOREX(sb, k & 1); }
        if (k + 4 < 16) LOADX(sb, k + 4);
        __syncthreads();
    }
#undef LOADX
#undef STOREX
#undef COMP

    float mv = acc[0]; int mi = 0;
#pragma unroll
    for (int k = 1; k < 16; ++k)
        if (acc[k] > mv) { mv = acc[k]; mi = k; }
    int n = (int)pxb + t;
    float x0 = x[n];
    float sig = 1.0f / (1.0f + expf(-x0));
    float sc = (sig > 0.5f) ? sig * mv : -INFINITY;
    score[n] = sc;
    clsidx[n] = mi;
    if (sc != -INFINITY) atomicAdd(&hist[fkey(sc) >> 16], 1u);
}

// ---------- K3: find 16-bit prefix p16 such that count(key>>16 >= p16) >= K ----------
__global__ __launch_bounds__(1024) void k_findp(const unsigned* __restrict__ hist,
                                                unsigned* __restrict__ meta) {
    __shared__ unsigned part[1024];
    __shared__ unsigned sgrp, s_after;
    __shared__ unsigned bins[64];
    int t = threadIdx.x;
    if (t == 0) { sgrp = 0; s_after = 0; }
    unsigned s = 0;
    const unsigned* hp = hist + t * 64;
    for (int i = 0; i < 64; ++i) s += hp[i];
    part[t] = s;
    __syncthreads();
    for (int off = 1; off < 1024; off <<= 1) {
        unsigned v = (t + off < 1024) ? part[t + off] : 0u;
        __syncthreads();
        part[t] += v;
        __syncthreads();
    }
    if (part[t] >= KSEL && (t == 1023 || part[t + 1] < KSEL)) {
        sgrp = (unsigned)t;
        s_after = (t == 1023) ? 0u : part[t + 1];
    }
    __syncthreads();
    unsigned g = sgrp, SA = s_after;
    if (t < 64) bins[t] = hist[g * 64 + t];
    __syncthreads();
    if (t == 0) {
        unsigned acc = SA, p = g * 64;
        for (int b = 63; b >= 0; --b) {
            acc += bins[b];
            if (acc >= KSEL) { p = g * 64 + (unsigned)b; break; }
        }
        meta[1] = p;
    }
}

// ---------- K4: collect candidates with key>>16 >= p16 ----------
__global__ void k_collect(const float* __restrict__ score,
                          unsigned* __restrict__ meta,
                          unsigned long long* __restrict__ cand) {
    int n = blockIdx.x * 256 + threadIdx.x;
    unsigned key = fkey(score[n]);
    if ((key >> 16) >= meta[1]) {
        unsigned pos = atomicAdd(&meta[0], 1u);
        if (pos < CAP)
            cand[pos] = ((unsigned long long)key << 32) | (unsigned)(~(unsigned)n);
    }
}

// ---------- K5: rank candidates (exact top-k ordering) + gather ----------
__global__ __launch_bounds__(256) void k_rank(const unsigned long long* __restrict__ cand,
                                              const unsigned* __restrict__ meta,
                                              const float* __restrict__ x,
                                              const float* __restrict__ score,
                                              const int* __restrict__ clsidx,
                                              float* __restrict__ topv,
                                              float* __restrict__ bl, float* __restrict__ bt,
                                              float* __restrict__ br, float* __restrict__ bb,
                                              float* __restrict__ area, int* __restrict__ clsk) {
    __shared__ unsigned long long tile[1024];
    int C = (int)meta[0]; if (C > CAP) C = CAP;
    int j = blockIdx.x * 256 + threadIdx.x;
    unsigned long long kj = (j < C) ? cand[j] : 0ull;
    unsigned rank = 0;
    for (int tb = 0; tb < C; tb += 1024) {
        int cnt = min(1024, C - tb);
        __syncthreads();
        for (int u = threadIdx.x; u < cnt; u += 256) tile[u] = cand[tb + u];
        __syncthreads();
        if (j < C)
            for (int u = 0; u < cnt; ++u) rank += (tile[u] > kj) ? 1u : 0u;
    }
    if (j < C && rank < KSEL) {
        unsigned n = ~(unsigned)(kj & 0xFFFFFFFFull);
        float l  = x[(size_t)1 * HW + n];
        float tt = x[(size_t)2 * HW + n];
        float r  = x[(size_t)3 * HW + n];
        float b  = x[(size_t)4 * HW + n];
        topv[rank] = score[n];
        bl[rank] = l; bt[rank] = tt; br[rank] = r; bb[rank] = b;
        area[rank] = (r - l) * (b - tt);
        clsk[rank] = clsidx[n];
    }
}

// ---------- K6: pairwise IoU >= 0.2 bitmask, ROW-MAJOR mask[i][w] ----------
__global__ __launch_bounds__(256) void k_mask(const float* __restrict__ bl, const float* __restrict__ bt,
                                              const float* __restrict__ br, const float* __restrict__ bb,
                                              const float* __restrict__ area,
                                              unsigned long long* __restrict__ mask) {
    __shared__ float sl[256], st[256], sr[256], sb[256], sa[256];
    int t = threadIdx.x;
    int ic = blockIdx.x >> 4;
    int jc = blockIdx.x & 15;
    int i = ic * 256 + t;
    int j0 = jc * 256;
    sl[t] = bl[j0 + t]; st[t] = bt[j0 + t]; sr[t] = br[j0 + t];
    sb[t] = bb[j0 + t]; sa[t] = area[j0 + t];
    __syncthreads();
    float li = bl[i], ti = bt[i], ri = br[i], bi = bb[i], ai = area[i];
#pragma unroll
    for (int w = 0; w < 4; ++w) {
        unsigned long long m = 0;
        for (int k2 = 0; k2 < 64; ++k2) {
            int j = w * 64 + k2;
            float iw = fminf(ri, sr[j]) - fmaxf(li, sl[j]); iw = fmaxf(iw, 0.f);
            float ih = fminf(bi, sb[j]) - fmaxf(ti, st[j]); ih = fmaxf(ih, 0.f);
            float inter = iw * ih;
            float uni = ai + sa[j] - inter + 1e-10f;
            if (inter / uni >= 0.2f) m |= (1ull << k2);
        }
        mask[(size_t)i * 64 + (jc * 4 + w)] = m;
    }
}

// ---------- K7: batched speculative NMS, 4 waves (r10 structure) + fused epilogue ----------
// Per batch: fresh-aliveL parallel pre-scan (256 threads) -> quad DPP reduce ->
// wave 0 ordered exact verify (4-at-a-time row preloads). Raw s_barrier +
// counted vmcnt(8) keeps the stage pipeline alive. Swizzle: logical word w of
// row r at phys (w + 2r) & 63; stage source permuted to match (rule #21).
__global__ __launch_bounds__(256, 1) void k_nms(const unsigned long long* __restrict__ mask,
                                                const float* __restrict__ topv,
                                                const float* __restrict__ area,
                                                const float* __restrict__ bl, const float* __restrict__ bt,
                                                const float* __restrict__ br, const float* __restrict__ bb,
                                                const int* __restrict__ clsk,
                                                const float* __restrict__ padding,
                                                const float* __restrict__ ratio,
                                                const int* __restrict__ piw, const int* __restrict__ pih,
                                                float* __restrict__ out) {
    __shared__ unsigned long long rowsL[2][4096];   // 2 x 32KB
    __shared__ unsigned long long aliveL[64];
    __shared__ unsigned long long keptL[64];
    __shared__ unsigned cntL[64];
    int t = threadIdx.x;
    int lane = t & 63;
    int W = t >> 6;
    int g = t & 3;          // word-group (16 logical words)
    int jrow = t >> 2;      // row in batch 0..63

    // ---- wave 0: init register-distributed alive/areaok; mirror alive to LDS
    unsigned long long alive = 0, areaok = 0, keptAcc = 0;
    if (W == 0) {
        for (int k = 0; k < 64; ++k) {
            float tv = topv[(size_t)k * 64 + lane];
            float ar = area[(size_t)k * 64 + lane];
            unsigned long long b1 = __ballot(tv != -INFINITY);
            unsigned long long b2 = __ballot(ar >= 4.0f);
            if (lane == k) { alive = b1; areaok = b2; }
        }
        aliveL[lane] = alive;
    }

    // ---- stage: 8 issues/wave; LDS dest linear, source pre-swizzled
#define STAGE(bb, s)                                                            \
    do {                                                                        \
        _Pragma("unroll") for (int i = 0; i < 8; ++i) {                         \
            int seg_ = i * 4 + W;                                               \
            int r_ = seg_ * 2 + (lane >> 5);                                    \
            int p_ = (lane & 31) * 2;                                           \
            int wl_ = (p_ - 2 * r_) & 63;                                       \
            const unsigned long long* gp_ =                                     \
                mask + ((size_t)((bb) * 64 + r_) * 64 + wl_);                   \
            __builtin_amdgcn_global_load_lds(                                   \
                (const __attribute__((address_space(1))) void*)gp_,             \
                (__attribute__((address_space(3))) void*)&rowsL[s][seg_ * 128], \
                16, 0, 0);                                                      \
        }                                                                       \
    } while (0)

    STAGE(0, 0);
    STAGE(1, 1);

#define VER(jj, rw)                                                             \
    {                                                                           \
        unsigned long long awc = readlane64(alive, b);                          \
        if ((awc >> (jj)) & 1ull) {                                             \
            unsigned long long awAdj = alive;                                   \
            unsigned long long pm = ((jj) == 63) ? ~0ull                        \
                                                 : ((1ull << ((jj) + 1)) - 1ull); \
            if (lane == b) awAdj &= ~pm;                                        \
            unsigned c_ = (unsigned)__popcll((rw) & awAdj);                     \
            unsigned tt_ = wave_sum64_s(c_);                                    \
            if (tt_ >= 10u) { alive &= ~(rw); keptB |= 1ull << (jj); }          \
        }                                                                       \
    }

    for (int b = 0; b < 64; ++b) {
        if (b < 63) asm volatile("s_waitcnt vmcnt(8)" ::: "memory");
        else        asm volatile("s_waitcnt vmcnt(0)" ::: "memory");
        __builtin_amdgcn_sched_barrier(0);
        __builtin_amdgcn_s_barrier();            // B1: stages + prev aliveL visible

        const unsigned long long* rb = &rowsL[b & 1][0];

        // ---- parallel pre-scan (fresh aliveL)
        unsigned long long pfxj = (jrow == 63) ? ~0ull : ((1ull << (jrow + 1)) - 1ull);
        int base_w = g * 16;
        unsigned cnt = 0;
#pragma unroll
        for (int q = 0; q < 8; ++q) {
            int wl = base_w + q * 2;                       // logical words wl, wl+1
            int ph = (wl + 2 * jrow) & 63;                 // phys (even, pair-contiguous)
            ulonglong2 rv = *(const ulonglong2*)&rb[jrow * 64 + ph];
            ulonglong2 av = *(const ulonglong2*)&aliveL[wl];
            unsigned cx = (unsigned)__popcll(rv.x & av.x);
            unsigned cy = (unsigned)__popcll(rv.y & av.y);
            cnt += cx + cy;
            if (wl == b)     cnt -= (unsigned)__popcll(rv.x & av.x & pfxj);
            if (wl + 1 == b) cnt -= (unsigned)__popcll(rv.y & av.y & pfxj);
        }
        // quad reduce (lanes j*4..j*4+3): quad_perm swaps
        cnt += (unsigned)__builtin_amdgcn_update_dpp(0, (int)cnt, 0xB1, 0xf, 0xf, false);
        cnt += (unsigned)__builtin_amdgcn_update_dpp(0, (int)cnt, 0x4E, 0xf, 0xf, false);
        if (g == 0) cntL[jrow] = cnt;
        asm volatile("s_waitcnt lgkmcnt(0)" ::: "memory");
        __builtin_amdgcn_s_barrier();            // B2: cntL ready

        // ---- wave 0: ordered exact verification
        if (W == 0) {
            unsigned long long keptB = 0;
            unsigned long long aw0snap = readlane64(alive, b);
            unsigned long long areaok0 = readlane64(areaok, b);
            unsigned myc = cntL[lane];
            bool candp = (myc >= 10u) && ((areaok0 >> lane) & 1ull) &&
                         ((aw0snap >> lane) & 1ull);
            unsigned long long cand = __ballot(candp);
            while (cand) {
                int j1 = __ffsll(cand) - 1; cand &= cand - 1;
                int j2 = -1, j3 = -1, j4 = -1;
                if (cand) { j2 = __ffsll(cand) - 1; cand &= cand - 1; }
                if (cand) { j3 = __ffsll(cand) - 1; cand &= cand - 1; }
                if (cand) { j4 = __ffsll(cand) - 1; cand &= cand - 1; }
                unsigned long long r1 = rb[j1 * 64 + ((lane + 2 * j1) & 63)];
                unsigned long long r2 = (j2 >= 0) ? rb[j2 * 64 + ((lane + 2 * j2) & 63)] : 0;
                unsigned long long r3 = (j3 >= 0) ? rb[j3 * 64 + ((lane + 2 * j3) & 63)] : 0;
                unsigned long long r4 = (j4 >= 0) ? rb[j4 * 64 + ((lane + 2 * j4) & 63)] : 0;
                VER(j1, r1);
                if (j2 >= 0) VER(j2, r2);
                if (j3 >= 0) VER(j3, r3);
                if (j4 >= 0) VER(j4, r4);
            }
            if (lane == b) { alive = 0; keptAcc = keptB; }
            aliveL[lane] = alive;
        }
        asm volatile("s_waitcnt lgkmcnt(0)" ::: "memory");
        __builtin_amdgcn_s_barrier();            // B3: aliveL ready; rowsL[cur] free
        if (b + 2 < 64) STAGE(b + 2, b & 1);
    }
    if (W == 0) keptL[lane] = keptAcc;
    __syncthreads();

    // ---- fused epilogue (was k_out)
    float p0 = padding[0], p1 = padding[1];
    float invr = 1.0f / ratio[0];
    float Wimg = (float)piw[0], Himg = (float)pih[0];
    for (int i = t; i < KSEL; i += 256) {
        bool kept = (keptL[i >> 6] >> (i & 63)) & 1ull;
        float tv = topv[i];
        bool keep = kept && (tv >= 0.5f);
        float x1 = fmaxf((bl[i] - p0) * invr, 0.f);
        float y1 = fmaxf((bt[i] - p1) * invr, 0.f);
        float x2 = fminf((br[i] - p0) * invr, Wimg);
        float y2 = fminf((bb[i] - p1) * invr, Himg);
        keep = keep && (x1 < Wimg) && (y1 < Himg);
        float* o = out + (size_t)i * 7;
        if (keep) {
            o[0] = 1.0f; o[1] = tv; o[2] = x1; o[3] = y1; o[4] = x2; o[5] = y2;
            o[6] = (float)clsk[i];
        } else {
            o[0] = 0.f; o[1] = 0.f; o[2] = 0.f; o[3] = 0.f; o[4] = 0.f; o[5] = 0.f; o[6] = 0.f;
        }
    }
#undef STAGE
#undef VER
}

extern "C" void kernel_launch(void* const* d_in, const int* in_sizes, int n_in,
                              void* d_out, int out_size, void* d_ws, size_t ws_size,
                              hipStream_t stream) {
    const float* x       = (const float*)d_in[0];
    const float* sm      = (const float*)d_in[1];
    const float* padding = (const float*)d_in[2];
    const float* ratio   = (const float*)d_in[3];
    const int*   piw     = (const int*)d_in[4];
    const int*   pih     = (const int*)d_in[5];
    float* out = (float*)d_out;
    char* ws = (char*)d_ws;

    // workspace layout (bytes)
    float* score               = (float*)(ws + 0);                 // 409600
    int*   clsidx              = (int*)(ws + 409600);              // 409600
    unsigned* hist             = (unsigned*)(ws + 819200);         // 262144
    unsigned* meta             = (unsigned*)(ws + 1081344);        // 512 (meta[0]=counter, meta[1]=p16)
    unsigned long long* cand   = (unsigned long long*)(ws + 1081856); // CAP*8 = 131072
    float* topv                = (float*)(ws + 1212928);           // 16384
    float* bl                  = (float*)(ws + 1229312);
    float* bt                  = (float*)(ws + 1245696);
    float* br                  = (float*)(ws + 1262080);
    float* bb                  = (float*)(ws + 1278464);
    float* area                = (float*)(ws + 1294848);
    int*   clsk                = (int*)(ws + 1311232);
    unsigned long long* mask   = (unsigned long long*)(ws + 1328128); // 2097152

    hipMemsetAsync(hist, 0, 262144 + 512, stream);  // hist + meta

    k_score  <<<800, 128, 0, stream>>>(x, sm, score, clsidx, hist);
    k_findp  <<<1, 1024, 0, stream>>>(hist, meta);
    k_collect<<<400, 256, 0, stream>>>(score, meta, cand);
    k_rank   <<<CAP / 256, 256, 0, stream>>>(cand, meta, x, score, clsidx,
                                             topv, bl, bt, br, bb, area, clsk);
    k_mask   <<<256, 256, 0, stream>>>(bl, bt, br, bb, area, mask);
    k_nms    <<<1, 256, 0, stream>>>(mask, topv, area, bl, bt, br, bb, clsk,
                                     padding, ratio, piw, pih, out);
}